// Round 8
// baseline (250.470 us; speedup 1.0000x reference)
//
#include <hip/hip_runtime.h>

#define B_ 16
#define N_ 16384
#define C_ 128
#define H_ 512
#define W_ 512
#define L_ 65
#define FG 64

// ws layout (float units)
#define OFF_SUMS 0
#define OFF_CNT  (B_*L_*C_)              // 133120 (ints live here after k_cent)
#define OFF_DIST (OFF_CNT + B_*L_)       // 134160
#define OFF_LAB  (OFF_DIST + B_*L_)      // 135200: B_*N_ ints (written by k_accum)
#define OFF_BCNT (OFF_LAB + B_*N_)       // 397344: 512*L_ ints (per-accum-block histograms)
#define OFF_PART (OFF_BCNT + 1024*L_)    // 463904: 512 slabs x L_*C_ partial sums (17 MB)

#define APB 512   // points per k_accum block
#define DPB 256   // points per k_dist block (1 per thread) -- R4 proven config

// pass 1: segment-sum with fused prep (R7 proven, +4us) and STEP-PARITY chain
// split (R8 experiment). Evidence: RMW-2copy, pipelined-RMW, and counting-sort
// cores all land ~53-59us vs ~25us memory floor. Discriminator: whole wave
// processes ONE point per step (float2/lane, contiguous 512B row load,
// conflict-free b64 RMW, zero intra-step races), accumulator copy indexed by
// step PARITY -> consecutive steps hit different copies -> the alias-forced
// serial chain splits into two independent interleaving 64-link chains.
// LDS size / occupancy / batching unchanged: single variable = chain ILP.
// R1 lesson: LDS f32 atomics ~200cyc effective -> never per-point.
// R5 lesson: never trade occupancy for staging amortization on BW-bound kernels.
__global__ __launch_bounds__(256) void k_accum(const float* __restrict__ emb,
                                               const int2* __restrict__ coords,
                                               const int* __restrict__ y,
                                               float* __restrict__ ws) {
    __shared__ __align__(16) float2 s_sum2[2 * L_ * 64];  // two copies (step parity)
    __shared__ int s_lab[APB];
    __shared__ int s_cnt[L_];
    const int b = blockIdx.x >> 5;            // 32 blocks per image
    const int base = (blockIdx.x & 31) * APB;
    const int t = threadIdx.x;
    const int wave = t >> 6;
    const int lane = t & 63;

    // fused prep: issue the scattered y-gather early, overlap with LDS zeroing
    const int g0 = b * N_ + base + t, g1 = g0 + 256;
    int2 r0 = coords[g0], r1 = coords[g1];
    if (t < L_) s_cnt[t] = 0;
    const float2 zero2 = {0.f, 0.f};
    for (int i = t; i < 2 * L_ * 64; i += 256) s_sum2[i] = zero2;
    int l0 = y[(b << 18) + (r0.x << 9) + r0.y];
    int l1 = y[(b << 18) + (r1.x << 9) + r1.y];
    __syncthreads();                          // s_cnt zeroed
    s_lab[t] = l0; s_lab[t + 256] = l1;
    ((int*)(ws + OFF_LAB))[g0] = l0;          // labels for k_dist (coalesced)
    ((int*)(ws + OFF_LAB))[g1] = l1;
    atomicAdd(&s_cnt[l0], 1);                 // native ds_add_u32
    atomicAdd(&s_cnt[l1], 1);
    __syncthreads();                          // s_lab + s_cnt + s_sum ready
    if (t < L_)
        ((int*)(ws + OFF_BCNT))[blockIdx.x * L_ + t] = s_cnt[t];

    // wave owns 128 consecutive points; 1 point (512B row) per step;
    // 16 batches of 8 steps, 2-deep named-buffer pipeline (proven skeleton).
    const float2* embp = (const float2*)(emb + (size_t)b * N_ * C_
                                         + (size_t)(base + wave * 128) * C_) + lane;
    const int* labp = s_lab + wave * 128;
    float2* cp0 = s_sum2 + lane;              // parity-0 copy, this lane's channels
    float2* cp1 = s_sum2 + L_ * 64 + lane;    // parity-1 copy

#define LOADB(e, lb, s) do {                                    \
        _Pragma("unroll")                                       \
        for (int u = 0; u < 8; ++u) {                           \
            int p = (s) * 8 + u;                                \
            e[u]  = embp[(size_t)p * 64];  /* 8B/lane, 512B/wave row */ \
            lb[u] = labp[p];               /* LDS broadcast */  \
        } } while (0)

// even u -> copy0 chain, odd u -> copy1 chain (batch start 8*s is even,
// so point parity == u parity); the two chains interleave
#define RMWB(e, lb) do {                                        \
        _Pragma("unroll")                                       \
        for (int u = 0; u < 8; ++u) {                           \
            float2* cp = (u & 1) ? cp1 : cp0;                   \
            float2 v = cp[lb[u] * 64];                          \
            v.x += e[u].x; v.y += e[u].y;                       \
            cp[lb[u] * 64] = v;                                 \
        } } while (0)

    float2 eA[8], eB[8]; int lbA[8], lbB[8];
    LOADB(eA, lbA, 0);
    for (int s0 = 1; s0 < 15; s0 += 2) {
        LOADB(eB, lbB, s0);
        RMWB(eA, lbA);
        LOADB(eA, lbA, s0 + 1);
        RMWB(eB, lbB);
    }
    LOADB(eB, lbB, 15);
    RMWB(eA, lbA);
    RMWB(eB, lbB);
#undef LOADB
#undef RMWB

    __syncthreads();
    // epilogue: sum the two parity copies, plain coalesced float4 slab stores
    float4* gp4 = (float4*)(ws + OFF_PART) + (size_t)blockIdx.x * (L_ * 32);
    const float4* ss = (const float4*)s_sum2;
    for (int i = t; i < L_ * 32; i += 256) {
        float4 a = ss[i], c = ss[L_ * 32 + i];
        a.x += c.x; a.y += c.y; a.z += c.z; a.w += c.w;
        gp4[i] = a;
    }
}

// per image: reduce per-block count histograms -> int counts; reduce the 32
// partial slabs -> sums; divide -> centroids (written to OFF_SUMS).
// Also absorbs old k_prep's zeroing duties: DIST and out (consumed later).
// 128 blocks: image b = blk>>3, chunk c = blk&7 (260 float4 of 2080 per image).
__global__ __launch_bounds__(256) void k_cent(float* __restrict__ ws,
                                              float* __restrict__ out) {
    __shared__ float s_inv[L_];
    const int b = blockIdx.x >> 3, c = blockIdx.x & 7;
    const int t = threadIdx.x;
    if (c == 0 && t < L_) ws[OFF_DIST + b * L_ + t] = 0.f;
    if (blockIdx.x == 0 && t == 0) out[0] = 0.f;
    if (t < L_) {
        const int* bc = (const int*)(ws + OFF_BCNT);
        int cnt = 0;
        #pragma unroll 8
        for (int k = 0; k < 32; ++k)
            cnt += bc[(b * 32 + k) * L_ + t];
        if (c == 0) ((int*)(ws + OFF_CNT))[b * L_ + t] = cnt;
        s_inv[t] = 1.f / fmaxf((float)cnt, 1.f);
    }
    __syncthreads();
    const float4* part = (const float4*)(ws + OFF_PART) + (size_t)b * 32 * (L_ * 32);
    float4* gs = (float4*)(ws + OFF_SUMS) + (size_t)b * (L_ * 32);
    for (int i4 = c * 260 + t; i4 < (c + 1) * 260 && i4 < L_ * 32; i4 += 256) {
        float4 s = {0.f, 0.f, 0.f, 0.f};
        #pragma unroll 8
        for (int s0 = 0; s0 < 32; ++s0) {
            float4 p = part[(size_t)s0 * (L_ * 32) + i4];
            s.x += p.x; s.y += p.y; s.z += p.z; s.w += p.w;
        }
        float inv = s_inv[(i4 * 4) >> 7];   // each float4 lies within one label row
        s.x *= inv; s.y *= inv; s.z *= inv; s.w *= inv;
        gs[i4] = s;
    }
}

// pass 2: point-per-lane, full 128-ch reduction in registers.
// R4 structure (256 threads, 1024 blocks, 4 blocks/CU = 16 waves/CU) --
// R5 proved halving occupancy here costs ~20us. Do not restructure.
__global__ __launch_bounds__(256) void k_dist(const float* __restrict__ emb,
                                              float* __restrict__ ws) {
    __shared__ __align__(16) float4 s_cent4[L_ * 33];  // row stride 33 float4
    __shared__ float s_dist[L_];
    const int b = blockIdx.x >> 6;                      // 64 blocks per image
    const int base = (blockIdx.x & 63) * DPB;

    const float* gcent = ws + OFF_SUMS + b * L_ * C_;
    for (int i = threadIdx.x; i < L_ * 32; i += 256) {
        int l = i >> 5, q = i & 31;
        s_cent4[l * 33 + q] = ((const float4*)gcent)[l * 32 + q];
    }
    if (threadIdx.x < L_) s_dist[threadIdx.x] = 0.f;
    __syncthreads();

    const int p = base + threadIdx.x;                   // this lane's point
    const int lb = ((const int*)(ws + OFF_LAB))[b * N_ + p];
    const float4* ep = (const float4*)(emb + (size_t)b * N_ * C_) + (size_t)p * 32;
    const float4* cp = s_cent4 + lb * 33;
    float acc = 0.f;
    #pragma unroll 8
    for (int q = 0; q < 32; ++q) {
        float4 e = ep[q], c = cp[q];
        float dx = e.x - c.x, dy = e.y - c.y;
        float dz = e.z - c.z, dw = e.w - c.w;
        acc += dx * dx + dy * dy + dz * dz + dw * dw;
    }
    unsafeAtomicAdd(&s_dist[lb], sqrtf(fmaxf(acc, 1e-12f)));
    __syncthreads();
    if (threadIdx.x < L_) {
        float d = s_dist[threadIdx.x];
        if (d != 0.f) unsafeAtomicAdd(ws + OFF_DIST + b * L_ + threadIdx.x, d);
    }
}

#define CSTRIDE 132  // 128 + 4 pad -> conflict-free float4 tile reads

__global__ __launch_bounds__(256) void k_final(float* __restrict__ ws, float* __restrict__ out) {
    __shared__ __align__(16) float s_cc[FG * CSTRIDE];
    __shared__ float s_present[FG];
    __shared__ float s_red[3];  // [0]=pull, [1]=push num, [2]=npairs
    const int b = blockIdx.x;
    const int t = threadIdx.x;

    const float* gcent = ws + OFF_SUMS + b * L_ * C_;
    for (int i = t; i < FG * C_; i += 256) {
        int l = i >> 7, ch = i & 127;
        s_cc[l * CSTRIDE + ch] = gcent[(l + 1) * C_ + ch];
    }
    if (t < 3) s_red[t] = 0.f;
    if (t < FG) {  // exactly wave 0
        int cnt = ((const int*)(ws + OFF_CNT))[b * L_ + 1 + t];
        s_present[t] = (cnt > 0) ? 1.f : 0.f;
        float pl = (cnt > 0) ? ws[OFF_DIST + b * L_ + 1 + t] / (float)cnt : 0.f;
        #pragma unroll
        for (int off = 32; off; off >>= 1) pl += __shfl_xor(pl, off);
        if (t == 0) s_red[0] = pl;
    }
    __syncthreads();

    const int wave = t >> 6, lane = t & 63;
    const int ti = lane >> 3, tj = lane & 7;
    float psum = 0.f, pnp = 0.f;
    for (int tt = wave; tt < 36; tt += 4) {
        int a = 0, c = tt;
        while (c >= 8 - a) { c -= 8 - a; ++a; }
        c += a;  // tile (a, c), a <= c
        int i = a * 8 + ti, jx = c * 8 + tj;
        float acc = 0.f;
        #pragma unroll
        for (int ch = 0; ch < C_; ch += 4) {
            float4 xi = *(const float4*)&s_cc[i * CSTRIDE + ch];
            float4 xj = *(const float4*)&s_cc[jx * CSTRIDE + ch];
            float dx = xi.x - xj.x, dy = xi.y - xj.y;
            float dz = xi.z - xj.z, dw = xi.w - xj.w;
            acc += dx * dx + dy * dy + dz * dz + dw * dw;
        }
        float dm = sqrtf(fmaxf(acc, 1e-12f));
        float pv = fmaxf(1.f - dm, 0.f);           // PUSH_MARGIN = 1
        bool valid = (i < jx) && (s_present[i] > 0.f) && (s_present[jx] > 0.f);
        if (valid) { psum += pv; pnp += 1.f; }
    }
    #pragma unroll
    for (int off = 32; off; off >>= 1) {
        psum += __shfl_xor(psum, off);
        pnp  += __shfl_xor(pnp,  off);
    }
    if (lane == 0) { unsafeAtomicAdd(&s_red[1], psum); unsafeAtomicAdd(&s_red[2], pnp); }
    __syncthreads();
    if (t == 0) {
        float loss = s_red[0] + s_red[1] / fmaxf(s_red[2], 1.f);
        unsafeAtomicAdd(out, loss);
    }
}

extern "C" void kernel_launch(void* const* d_in, const int* in_sizes, int n_in,
                              void* d_out, int out_size, void* d_ws, size_t ws_size,
                              hipStream_t stream) {
    const float* emb   = (const float*)d_in[0];
    const int2* coords = (const int2*)d_in[1];
    const int*  y      = (const int*)d_in[2];
    float* out = (float*)d_out;
    float* ws  = (float*)d_ws;

    k_accum<<<B_ * (N_ / APB), 256, 0, stream>>>(emb, coords, y, ws);
    k_cent<<<B_ * 8, 256, 0, stream>>>(ws, out);
    k_dist<<<B_ * (N_ / DPB), 256, 0, stream>>>(emb, ws);
    k_final<<<B_, 256, 0, stream>>>(ws, out);
}

// Round 9
// 246.425 us; speedup vs baseline: 1.0164x; 1.0164x over previous
//
#include <hip/hip_runtime.h>

#define B_ 16
#define N_ 16384
#define C_ 128
#define H_ 512
#define W_ 512
#define L_ 65
#define FG 64

// ws layout (float units)
#define OFF_SUMS 0
#define OFF_CNT  (B_*L_*C_)              // 133120 (ints live here after k_cent)
#define OFF_DIST (OFF_CNT + B_*L_)       // 134160
#define OFF_LAB  (OFF_DIST + B_*L_)      // 135200: B_*N_ ints (written by k_accum)
#define OFF_BCNT (OFF_LAB + B_*N_)       // 397344: 512*L_ ints (per-accum-block histograms)
#define OFF_PART (OFF_BCNT + 1024*L_)    // 463904: 512 slabs x L_*C_ partial sums (17 MB)

#define APB 512   // points per k_accum block
#define DPB 256   // points per k_dist block (1 per thread) -- R4 proven config

// pass 1: segment-sum, R7 core (b128 LDS RMW, per-half copies, fused prep)
// with ONE variable changed for R9: 512 threads / 8 waves per block (was 256/4).
// Same 68.9KB LDS, same 512-block grid -> still 2 blocks/CU, but 16 waves/CU
// = 4 waves/SIMD (was 2). Rationale: four structurally different cores
// (2-copy RMW R2/R7, pipelined RMW R2, counting sort R3, parity-split R8) all
// land ~53us vs ~25us memory floor -> bottleneck is invariant to LDS/chain
// structure; the only never-varied shared factor is 8 waves/CU of latency
// hiding. R5 proved the same mechanism in reverse on k_dist (16->8 waves/CU
// cost ~20us on a 134MB stream).
// R1 lesson: LDS f32 atomics ~200cyc effective -> never per-point.
__global__ __launch_bounds__(512) void k_accum(const float* __restrict__ emb,
                                               const int2* __restrict__ coords,
                                               const int* __restrict__ y,
                                               float* __restrict__ ws) {
    __shared__ float4 s_sum4[2 * L_ * 32];   // two copies, plain row layout
    __shared__ int s_lab[APB];
    __shared__ int s_cnt[L_];
    const int b = blockIdx.x >> 5;            // 32 blocks per image
    const int base = (blockIdx.x & 31) * APB;
    const int t = threadIdx.x;
    const int wave = t >> 6;                  // 0..7
    const int lane = t & 63;
    const int half = lane >> 5, j = lane & 31;

    // fused prep: one point per thread; scattered y-gather overlaps LDS zeroing
    const int g0 = b * N_ + base + t;
    int2 r0 = coords[g0];
    if (t < L_) s_cnt[t] = 0;
    const float4 zero4 = {0.f, 0.f, 0.f, 0.f};
    for (int i = t; i < 2 * L_ * 32; i += 512) s_sum4[i] = zero4;
    int l0 = y[(b << 18) + (r0.x << 9) + r0.y];
    __syncthreads();                          // s_cnt zeroed
    s_lab[t] = l0;
    ((int*)(ws + OFF_LAB))[g0] = l0;          // labels for k_dist (coalesced)
    atomicAdd(&s_cnt[l0], 1);                 // native ds_add_u32
    __syncthreads();                          // s_lab + s_cnt + s_sum ready
    if (t < L_)
        ((int*)(ws + OFF_BCNT))[blockIdx.x * L_ + t] = s_cnt[t];

    // wave owns 64 consecutive points; 2 points (1KB) per step, 8 steps/batch
    const float4* embp = (const float4*)(emb + (size_t)b * N_ * C_
                                         + (size_t)(base + wave * (APB / 8)) * C_) + j;
    const int* labp = s_lab + wave * (APB / 8);
    float4* copy = s_sum4 + half * (L_ * 32) + j;

#define LOADB(e, lb, s) do {                                   \
        _Pragma("unroll")                                      \
        for (int u = 0; u < 8; ++u) {                          \
            int p = 2 * ((s) * 8 + u) + half;                  \
            e[u]  = embp[(size_t)p * 32];  /* 16B/lane, 1KB/wave */ \
            lb[u] = labp[p];               /* LDS broadcast */ \
        } } while (0)

#define RMWB(e, lb) do {                                       \
        _Pragma("unroll")                                      \
        for (int u = 0; u < 8; ++u) {                          \
            float4 v = copy[lb[u] * 32];                       \
            v.x += e[u].x; v.y += e[u].y;                      \
            v.z += e[u].z; v.w += e[u].w;                      \
            copy[lb[u] * 32] = v;                              \
        } } while (0)

    float4 eA[8], eB[8]; int lbA[8], lbB[8];   // 4 batches of 8 steps (64 pts)
    LOADB(eA, lbA, 0);
    LOADB(eB, lbB, 1);
    RMWB(eA, lbA);
    LOADB(eA, lbA, 2);
    RMWB(eB, lbB);
    LOADB(eB, lbB, 3);
    RMWB(eA, lbA);
    RMWB(eB, lbB);
#undef LOADB
#undef RMWB

    __syncthreads();
    // epilogue: plain coalesced float4 stores to this block's private slab
    float4* gp4 = (float4*)(ws + OFF_PART) + (size_t)blockIdx.x * (L_ * 32);
    for (int i = t; i < L_ * 32; i += 512) {
        float4 a = s_sum4[i], c = s_sum4[L_ * 32 + i];
        a.x += c.x; a.y += c.y; a.z += c.z; a.w += c.w;
        gp4[i] = a;
    }
}

// per image: reduce per-block count histograms -> int counts; reduce the 32
// partial slabs -> sums; divide -> centroids (written to OFF_SUMS).
// Also absorbs old k_prep's zeroing duties: DIST and out (consumed later).
// 128 blocks: image b = blk>>3, chunk c = blk&7 (260 float4 of 2080 per image).
__global__ __launch_bounds__(256) void k_cent(float* __restrict__ ws,
                                              float* __restrict__ out) {
    __shared__ float s_inv[L_];
    const int b = blockIdx.x >> 3, c = blockIdx.x & 7;
    const int t = threadIdx.x;
    if (c == 0 && t < L_) ws[OFF_DIST + b * L_ + t] = 0.f;
    if (blockIdx.x == 0 && t == 0) out[0] = 0.f;
    if (t < L_) {
        const int* bc = (const int*)(ws + OFF_BCNT);
        int cnt = 0;
        #pragma unroll 8
        for (int k = 0; k < 32; ++k)
            cnt += bc[(b * 32 + k) * L_ + t];
        if (c == 0) ((int*)(ws + OFF_CNT))[b * L_ + t] = cnt;
        s_inv[t] = 1.f / fmaxf((float)cnt, 1.f);
    }
    __syncthreads();
    const float4* part = (const float4*)(ws + OFF_PART) + (size_t)b * 32 * (L_ * 32);
    float4* gs = (float4*)(ws + OFF_SUMS) + (size_t)b * (L_ * 32);
    for (int i4 = c * 260 + t; i4 < (c + 1) * 260 && i4 < L_ * 32; i4 += 256) {
        float4 s = {0.f, 0.f, 0.f, 0.f};
        #pragma unroll 8
        for (int s0 = 0; s0 < 32; ++s0) {
            float4 p = part[(size_t)s0 * (L_ * 32) + i4];
            s.x += p.x; s.y += p.y; s.z += p.z; s.w += p.w;
        }
        float inv = s_inv[(i4 * 4) >> 7];   // each float4 lies within one label row
        s.x *= inv; s.y *= inv; s.z *= inv; s.w *= inv;
        gs[i4] = s;
    }
}

// pass 2: point-per-lane, full 128-ch reduction in registers.
// R4 structure (256 threads, 1024 blocks, 4 blocks/CU = 16 waves/CU) --
// R5 proved halving occupancy here costs ~20us. Do not restructure.
__global__ __launch_bounds__(256) void k_dist(const float* __restrict__ emb,
                                              float* __restrict__ ws) {
    __shared__ __align__(16) float4 s_cent4[L_ * 33];  // row stride 33 float4
    __shared__ float s_dist[L_];
    const int b = blockIdx.x >> 6;                      // 64 blocks per image
    const int base = (blockIdx.x & 63) * DPB;

    const float* gcent = ws + OFF_SUMS + b * L_ * C_;
    for (int i = threadIdx.x; i < L_ * 32; i += 256) {
        int l = i >> 5, q = i & 31;
        s_cent4[l * 33 + q] = ((const float4*)gcent)[l * 32 + q];
    }
    if (threadIdx.x < L_) s_dist[threadIdx.x] = 0.f;
    __syncthreads();

    const int p = base + threadIdx.x;                   // this lane's point
    const int lb = ((const int*)(ws + OFF_LAB))[b * N_ + p];
    const float4* ep = (const float4*)(emb + (size_t)b * N_ * C_) + (size_t)p * 32;
    const float4* cp = s_cent4 + lb * 33;
    float acc = 0.f;
    #pragma unroll 8
    for (int q = 0; q < 32; ++q) {
        float4 e = ep[q], c = cp[q];
        float dx = e.x - c.x, dy = e.y - c.y;
        float dz = e.z - c.z, dw = e.w - c.w;
        acc += dx * dx + dy * dy + dz * dz + dw * dw;
    }
    unsafeAtomicAdd(&s_dist[lb], sqrtf(fmaxf(acc, 1e-12f)));
    __syncthreads();
    if (threadIdx.x < L_) {
        float d = s_dist[threadIdx.x];
        if (d != 0.f) unsafeAtomicAdd(ws + OFF_DIST + b * L_ + threadIdx.x, d);
    }
}

#define CSTRIDE 132  // 128 + 4 pad -> conflict-free float4 tile reads

__global__ __launch_bounds__(256) void k_final(float* __restrict__ ws, float* __restrict__ out) {
    __shared__ __align__(16) float s_cc[FG * CSTRIDE];
    __shared__ float s_present[FG];
    __shared__ float s_red[3];  // [0]=pull, [1]=push num, [2]=npairs
    const int b = blockIdx.x;
    const int t = threadIdx.x;

    const float* gcent = ws + OFF_SUMS + b * L_ * C_;
    for (int i = t; i < FG * C_; i += 256) {
        int l = i >> 7, ch = i & 127;
        s_cc[l * CSTRIDE + ch] = gcent[(l + 1) * C_ + ch];
    }
    if (t < 3) s_red[t] = 0.f;
    if (t < FG) {  // exactly wave 0
        int cnt = ((const int*)(ws + OFF_CNT))[b * L_ + 1 + t];
        s_present[t] = (cnt > 0) ? 1.f : 0.f;
        float pl = (cnt > 0) ? ws[OFF_DIST + b * L_ + 1 + t] / (float)cnt : 0.f;
        #pragma unroll
        for (int off = 32; off; off >>= 1) pl += __shfl_xor(pl, off);
        if (t == 0) s_red[0] = pl;
    }
    __syncthreads();

    const int wave = t >> 6, lane = t & 63;
    const int ti = lane >> 3, tj = lane & 7;
    float psum = 0.f, pnp = 0.f;
    for (int tt = wave; tt < 36; tt += 4) {
        int a = 0, c = tt;
        while (c >= 8 - a) { c -= 8 - a; ++a; }
        c += a;  // tile (a, c), a <= c
        int i = a * 8 + ti, jx = c * 8 + tj;
        float acc = 0.f;
        #pragma unroll
        for (int ch = 0; ch < C_; ch += 4) {
            float4 xi = *(const float4*)&s_cc[i * CSTRIDE + ch];
            float4 xj = *(const float4*)&s_cc[jx * CSTRIDE + ch];
            float dx = xi.x - xj.x, dy = xi.y - xj.y;
            float dz = xi.z - xj.z, dw = xi.w - xj.w;
            acc += dx * dx + dy * dy + dz * dz + dw * dw;
        }
        float dm = sqrtf(fmaxf(acc, 1e-12f));
        float pv = fmaxf(1.f - dm, 0.f);           // PUSH_MARGIN = 1
        bool valid = (i < jx) && (s_present[i] > 0.f) && (s_present[jx] > 0.f);
        if (valid) { psum += pv; pnp += 1.f; }
    }
    #pragma unroll
    for (int off = 32; off; off >>= 1) {
        psum += __shfl_xor(psum, off);
        pnp  += __shfl_xor(pnp,  off);
    }
    if (lane == 0) { unsafeAtomicAdd(&s_red[1], psum); unsafeAtomicAdd(&s_red[2], pnp); }
    __syncthreads();
    if (t == 0) {
        float loss = s_red[0] + s_red[1] / fmaxf(s_red[2], 1.f);
        unsafeAtomicAdd(out, loss);
    }
}

extern "C" void kernel_launch(void* const* d_in, const int* in_sizes, int n_in,
                              void* d_out, int out_size, void* d_ws, size_t ws_size,
                              hipStream_t stream) {
    const float* emb   = (const float*)d_in[0];
    const int2* coords = (const int2*)d_in[1];
    const int*  y      = (const int*)d_in[2];
    float* out = (float*)d_out;
    float* ws  = (float*)d_ws;

    k_accum<<<B_ * (N_ / APB), 512, 0, stream>>>(emb, coords, y, ws);
    k_cent<<<B_ * 8, 256, 0, stream>>>(ws, out);
    k_dist<<<B_ * (N_ / DPB), 256, 0, stream>>>(emb, ws);
    k_final<<<B_, 256, 0, stream>>>(ws, out);
}